// Round 3
// baseline (1460.536 us; speedup 1.0000x reference)
//
#include <hip/hip_runtime.h>
#include <cstddef>

#define CC 128  // channels

// ---------------------------------------------------------------------------
// Edge scatter, single pass. 1 wave per edge, 2 channels per lane.
//   outR[r] += lr*Xr[c] - li*Xi[c]
//   outI[r] += li*Xr[c] + lr*Xi[c]
// out is the f32 output buffer [2N][128], pre-zeroed; HW f32 atomics.
// ---------------------------------------------------------------------------
__global__ __launch_bounds__(256) void scatter_edges(
    const float* __restrict__ Xr,
    const float* __restrict__ Xi,
    const float* __restrict__ Lr,
    const float* __restrict__ Li,
    const int* __restrict__ row,
    const int* __restrict__ col,
    float* __restrict__ out,            // [2N][128] f32, pre-zeroed
    int N, int E)
{
    const int e = blockIdx.x * 4 + (threadIdx.x >> 6);
    if (e >= E) return;
    const int lane = threadIdx.x & 63;
    const int r = row[e], c = col[e];
    const float lr = Lr[e];
    const float li = Li[e];
    const float2 xr = *(const float2*)(Xr + (size_t)c * CC + 2 * lane);
    const float2 xi = *(const float2*)(Xi + (size_t)c * CC + 2 * lane);
    float* pr = out + (size_t)r * CC + 2 * lane;
    float* pi = out + ((size_t)r + N) * CC + 2 * lane;
    unsafeAtomicAdd(pr,     lr * xr.x - li * xi.x);
    unsafeAtomicAdd(pr + 1, lr * xr.y - li * xi.y);
    unsafeAtomicAdd(pi,     li * xr.x + lr * xi.x);
    unsafeAtomicAdd(pi + 1, li * xr.y + lr * xi.y);
}

// ---------------------------------------------------------------------------
// In-place dense projection + residual on one half:
//   io[m][:] = io[m][:] @ W + Xp[m][:]
// Row-local => in-place across blocks is safe. Block: 256 threads, 32 rows.
// W staged in LDS in two 64-row chunks (32 KB); block's 32 io-rows staged
// transposed in padded LDS (18 KB). 4x4 register blocking per thread.
// ---------------------------------------------------------------------------
__global__ __launch_bounds__(256) void gemm_inplace(
    float* __restrict__ io,             // [N][128] f32: in agg, out result
    const float* __restrict__ W,        // [128][128] f32
    const float* __restrict__ Xp,       // [N][128] f32 residual
    int N)
{
    __shared__ float Ws[64 * CC];       // 32 KB (one 64-row K-chunk of W)
    __shared__ float AsT[CC][36];       // 18 KB, [k][r], pad->2-way max (free)
    const int t = threadIdx.x;
    const int m0 = blockIdx.x * 32;

    // Stage this block's 32 rows of io, transposed. 1024 float4 chunks.
    for (int ch = t; ch < 1024; ch += 256) {
        const int r  = ch >> 5;         // 0..31
        const int k0 = (ch & 31) * 4;   // 0..124
        const int m  = m0 + r;
        float4 q = make_float4(0.f, 0.f, 0.f, 0.f);
        if (m < N) q = *(const float4*)(io + (size_t)m * CC + k0);
        AsT[k0 + 0][r] = q.x;
        AsT[k0 + 1][r] = q.y;
        AsT[k0 + 2][r] = q.z;
        AsT[k0 + 3][r] = q.w;
    }

    const int cg = t & 31;   // cols cg*4 .. cg*4+3
    const int rs = t >> 5;   // rows rs*4 .. rs*4+3
    float s[4][4];
    #pragma unroll
    for (int a = 0; a < 4; ++a)
        #pragma unroll
        for (int b = 0; b < 4; ++b) s[a][b] = 0.f;

    for (int kc = 0; kc < 2; ++kc) {
        __syncthreads();   // AsT ready (kc=0) / all done reading old Ws (kc=1)
        {   // W rows kc*64 .. kc*64+63 -> LDS: 2048 float4, 8 per thread
            const float4* src = (const float4*)(W + (size_t)kc * 64 * CC);
            float4* dst = (float4*)Ws;
            #pragma unroll
            for (int i = 0; i < 8; ++i) dst[t + 256 * i] = src[t + 256 * i];
        }
        __syncthreads();

        #pragma unroll 4
        for (int kk = 0; kk < 64; ++kk) {
            const int k = kc * 64 + kk;
            const float4 av = *(const float4*)&AsT[k][rs * 4];      // 4 rows
            const float4 wv = *(const float4*)&Ws[kk * CC + cg * 4]; // 4 cols
            const float ar[4] = {av.x, av.y, av.z, av.w};
            const float wc[4] = {wv.x, wv.y, wv.z, wv.w};
            #pragma unroll
            for (int a = 0; a < 4; ++a)
                #pragma unroll
                for (int b = 0; b < 4; ++b) s[a][b] += ar[a] * wc[b];
        }
    }

    #pragma unroll
    for (int a = 0; a < 4; ++a) {
        const int m = m0 + rs * 4 + a;
        if (m >= N) continue;
        const float4 xv = *(const float4*)(Xp + (size_t)m * CC + cg * 4);
        float4 o;
        o.x = s[a][0] + xv.x;
        o.y = s[a][1] + xv.y;
        o.z = s[a][2] + xv.z;
        o.w = s[a][3] + xv.w;
        *(float4*)(io + (size_t)m * CC + cg * 4) = o;
    }
}

extern "C" void kernel_launch(void* const* d_in, const int* in_sizes, int n_in,
                              void* d_out, int out_size, void* d_ws, size_t ws_size,
                              hipStream_t stream)
{
    const float* Xr = (const float*)d_in[0];
    const float* Xi = (const float*)d_in[1];
    const float* Lr = (const float*)d_in[2];
    const float* Li = (const float*)d_in[3];
    const float* W  = (const float*)d_in[4];
    const int* row = (const int*)d_in[5];
    const int* col = (const int*)d_in[6];
    float* out = (float*)d_out;

    const int N = in_sizes[0] / CC;     // 50000
    const int E = in_sizes[2];          // 800000

    // out doubles as the f32 scatter accumulator: [0..N) real, [N..2N) imag.
    hipMemsetAsync(out, 0, (size_t)2 * N * CC * sizeof(float), stream);
    scatter_edges<<<dim3((E + 3) / 4), dim3(256), 0, stream>>>(
        Xr, Xi, Lr, Li, row, col, out, N, E);
    // In-place projection + residual, per half.
    gemm_inplace<<<dim3((N + 31) / 32), dim3(256), 0, stream>>>(
        out, W, Xr, N);
    gemm_inplace<<<dim3((N + 31) / 32), dim3(256), 0, stream>>>(
        out + (size_t)N * CC, W, Xi, N);
}

// Round 4
// 455.866 us; speedup vs baseline: 3.2039x; 3.2039x over previous
//
#include <hip/hip_runtime.h>
#include <cstddef>

#define CC 128  // channels

// ===========================================================================
// CSR-build + gather path (no fp atomics)
// ===========================================================================

__global__ __launch_bounds__(256) void hist_rows(
    const int* __restrict__ row, int* __restrict__ counts, int E)
{
    const int e = blockIdx.x * 256 + threadIdx.x;
    if (e < E) atomicAdd(counts + row[e], 1);
}

// Single-block exclusive scan of counts[N] -> offsets[N]. 1024 threads,
// each owns a contiguous run of ceil(N/1024) elements.
__global__ __launch_bounds__(1024) void scan_offsets(
    const int* __restrict__ counts, int* __restrict__ offsets, int N)
{
    __shared__ int sums[1024];
    const int t = threadIdx.x;
    const int per = (N + 1023) / 1024;
    const int start = t * per;
    int s = 0;
    for (int i = 0; i < per; ++i) {
        const int idx = start + i;
        if (idx < N) s += counts[idx];
    }
    sums[t] = s;
    __syncthreads();
    // Hillis-Steele inclusive scan over 1024 entries
    for (int off = 1; off < 1024; off <<= 1) {
        const int v = sums[t];
        const int u = (t >= off) ? sums[t - off] : 0;
        __syncthreads();
        sums[t] = v + u;
        __syncthreads();
    }
    int excl = (t == 0) ? 0 : sums[t - 1];
    for (int i = 0; i < per; ++i) {
        const int idx = start + i;
        if (idx < N) {
            offsets[idx] = excl;
            excl += counts[idx];
        }
    }
}

// Scatter packed edge records {col, lr, li, 0} into CSR slots.
__global__ __launch_bounds__(256) void fill_csr(
    const int* __restrict__ row, const int* __restrict__ col,
    const float* __restrict__ Lr, const float* __restrict__ Li,
    const int* __restrict__ offsets, int* __restrict__ cursor,
    int4* __restrict__ meta, int E)
{
    const int e = blockIdx.x * 256 + threadIdx.x;
    if (e >= E) return;
    const int r = row[e];
    const int pos = offsets[r] + atomicAdd(cursor + r, 1);
    meta[pos] = make_int4(col[e], __float_as_int(Lr[e]), __float_as_int(Li[e]), 0);
}

// One wave per node; lane handles 2 channels. Accumulate real+imag in regs.
//   outR[n] = sum_e lr*Xr[c] - li*Xi[c];  outI[n] = sum_e li*Xr[c] + lr*Xi[c]
__global__ __launch_bounds__(256) void gather_nodes(
    const float* __restrict__ Xr, const float* __restrict__ Xi,
    const int* __restrict__ offsets, const int4* __restrict__ meta,
    float* __restrict__ out, int N, int E)
{
    const int n = blockIdx.x * 4 + (threadIdx.x >> 6);
    if (n >= N) return;
    const int lane = threadIdx.x & 63;
    const int start = offsets[n];
    const int end   = (n + 1 < N) ? offsets[n + 1] : E;
    float2 aR = make_float2(0.f, 0.f);
    float2 aI = make_float2(0.f, 0.f);

    int j = start;
    for (; j + 2 <= end; j += 2) {   // 2-wide unroll for MLP
        const int4 m0 = meta[j];
        const int4 m1 = meta[j + 1];
        const float2 xr0 = *(const float2*)(Xr + (size_t)m0.x * CC + 2 * lane);
        const float2 xi0 = *(const float2*)(Xi + (size_t)m0.x * CC + 2 * lane);
        const float2 xr1 = *(const float2*)(Xr + (size_t)m1.x * CC + 2 * lane);
        const float2 xi1 = *(const float2*)(Xi + (size_t)m1.x * CC + 2 * lane);
        const float lr0 = __int_as_float(m0.y), li0 = __int_as_float(m0.z);
        const float lr1 = __int_as_float(m1.y), li1 = __int_as_float(m1.z);
        aR.x += lr0 * xr0.x - li0 * xi0.x;
        aR.y += lr0 * xr0.y - li0 * xi0.y;
        aI.x += li0 * xr0.x + lr0 * xi0.x;
        aI.y += li0 * xr0.y + lr0 * xi0.y;
        aR.x += lr1 * xr1.x - li1 * xi1.x;
        aR.y += lr1 * xr1.y - li1 * xi1.y;
        aI.x += li1 * xr1.x + lr1 * xi1.x;
        aI.y += li1 * xr1.y + lr1 * xi1.y;
    }
    if (j < end) {
        const int4 m0 = meta[j];
        const float2 xr0 = *(const float2*)(Xr + (size_t)m0.x * CC + 2 * lane);
        const float2 xi0 = *(const float2*)(Xi + (size_t)m0.x * CC + 2 * lane);
        const float lr0 = __int_as_float(m0.y), li0 = __int_as_float(m0.z);
        aR.x += lr0 * xr0.x - li0 * xi0.x;
        aR.y += lr0 * xr0.y - li0 * xi0.y;
        aI.x += li0 * xr0.x + lr0 * xi0.x;
        aI.y += li0 * xr0.y + lr0 * xi0.y;
    }
    *(float2*)(out + (size_t)n * CC + 2 * lane) = aR;
    *(float2*)(out + ((size_t)n + N) * CC + 2 * lane) = aI;
}

// ===========================================================================
// Fallback: atomic scatter (round-3 proven path)
// ===========================================================================
__global__ __launch_bounds__(256) void scatter_edges(
    const float* __restrict__ Xr, const float* __restrict__ Xi,
    const float* __restrict__ Lr, const float* __restrict__ Li,
    const int* __restrict__ row, const int* __restrict__ col,
    float* __restrict__ out, int N, int E)
{
    const int e = blockIdx.x * 4 + (threadIdx.x >> 6);
    if (e >= E) return;
    const int lane = threadIdx.x & 63;
    const int r = row[e], c = col[e];
    const float lr = Lr[e];
    const float li = Li[e];
    const float2 xr = *(const float2*)(Xr + (size_t)c * CC + 2 * lane);
    const float2 xi = *(const float2*)(Xi + (size_t)c * CC + 2 * lane);
    float* pr = out + (size_t)r * CC + 2 * lane;
    float* pi = out + ((size_t)r + N) * CC + 2 * lane;
    unsafeAtomicAdd(pr,     lr * xr.x - li * xi.x);
    unsafeAtomicAdd(pr + 1, lr * xr.y - li * xi.y);
    unsafeAtomicAdd(pi,     li * xr.x + lr * xi.x);
    unsafeAtomicAdd(pi + 1, li * xr.y + lr * xi.y);
}

// ===========================================================================
// In-place dense projection + residual on one half: io = io@W + Xp
// ===========================================================================
__global__ __launch_bounds__(256) void gemm_inplace(
    float* __restrict__ io,             // [N][128] f32: in agg, out result
    const float* __restrict__ W,        // [128][128] f32
    const float* __restrict__ Xp,       // [N][128] f32 residual
    int N)
{
    __shared__ float Ws[64 * CC];       // 32 KB (one 64-row K-chunk of W)
    __shared__ float AsT[CC][36];       // 18 KB, [k][r]
    const int t = threadIdx.x;
    const int m0 = blockIdx.x * 32;

    for (int ch = t; ch < 1024; ch += 256) {
        const int r  = ch >> 5;
        const int k0 = (ch & 31) * 4;
        const int m  = m0 + r;
        float4 q = make_float4(0.f, 0.f, 0.f, 0.f);
        if (m < N) q = *(const float4*)(io + (size_t)m * CC + k0);
        AsT[k0 + 0][r] = q.x;
        AsT[k0 + 1][r] = q.y;
        AsT[k0 + 2][r] = q.z;
        AsT[k0 + 3][r] = q.w;
    }

    const int cg = t & 31;
    const int rs = t >> 5;
    float s[4][4];
    #pragma unroll
    for (int a = 0; a < 4; ++a)
        #pragma unroll
        for (int b = 0; b < 4; ++b) s[a][b] = 0.f;

    for (int kc = 0; kc < 2; ++kc) {
        __syncthreads();
        {
            const float4* src = (const float4*)(W + (size_t)kc * 64 * CC);
            float4* dst = (float4*)Ws;
            #pragma unroll
            for (int i = 0; i < 8; ++i) dst[t + 256 * i] = src[t + 256 * i];
        }
        __syncthreads();

        #pragma unroll 4
        for (int kk = 0; kk < 64; ++kk) {
            const int k = kc * 64 + kk;
            const float4 av = *(const float4*)&AsT[k][rs * 4];
            const float4 wv = *(const float4*)&Ws[kk * CC + cg * 4];
            const float ar[4] = {av.x, av.y, av.z, av.w};
            const float wc[4] = {wv.x, wv.y, wv.z, wv.w};
            #pragma unroll
            for (int a = 0; a < 4; ++a)
                #pragma unroll
                for (int b = 0; b < 4; ++b) s[a][b] += ar[a] * wc[b];
        }
    }

    #pragma unroll
    for (int a = 0; a < 4; ++a) {
        const int m = m0 + rs * 4 + a;
        if (m >= N) continue;
        const float4 xv = *(const float4*)(Xp + (size_t)m * CC + cg * 4);
        float4 o;
        o.x = s[a][0] + xv.x;
        o.y = s[a][1] + xv.y;
        o.z = s[a][2] + xv.z;
        o.w = s[a][3] + xv.w;
        *(float4*)(io + (size_t)m * CC + cg * 4) = o;
    }
}

extern "C" void kernel_launch(void* const* d_in, const int* in_sizes, int n_in,
                              void* d_out, int out_size, void* d_ws, size_t ws_size,
                              hipStream_t stream)
{
    const float* Xr = (const float*)d_in[0];
    const float* Xi = (const float*)d_in[1];
    const float* Lr = (const float*)d_in[2];
    const float* Li = (const float*)d_in[3];
    const float* W  = (const float*)d_in[4];
    const int* row = (const int*)d_in[5];
    const int* col = (const int*)d_in[6];
    float* out = (float*)d_out;

    const int N = in_sizes[0] / CC;     // 50000
    const int E = in_sizes[2];          // 800000

    // ws layout: meta int4[E] | counts[N] | cursor[N] | offsets[N+1]
    const size_t need = (size_t)E * 16 + (size_t)(3 * N + 2) * 4;
    if (ws_size >= need) {
        int4* meta    = (int4*)d_ws;
        int*  counts  = (int*)((char*)d_ws + (size_t)E * 16);
        int*  cursor  = counts + N;
        int*  offsets = cursor + N;

        hipMemsetAsync(counts, 0, (size_t)2 * N * sizeof(int), stream);  // counts+cursor
        hist_rows<<<dim3((E + 255) / 256), dim3(256), 0, stream>>>(row, counts, E);
        scan_offsets<<<dim3(1), dim3(1024), 0, stream>>>(counts, offsets, N);
        fill_csr<<<dim3((E + 255) / 256), dim3(256), 0, stream>>>(
            row, col, Lr, Li, offsets, cursor, meta, E);
        gather_nodes<<<dim3((N + 3) / 4), dim3(256), 0, stream>>>(
            Xr, Xi, offsets, meta, out, N, E);
    } else {
        // Fallback: atomic scatter into zeroed out
        hipMemsetAsync(out, 0, (size_t)2 * N * CC * sizeof(float), stream);
        scatter_edges<<<dim3((E + 3) / 4), dim3(256), 0, stream>>>(
            Xr, Xi, Lr, Li, row, col, out, N, E);
    }

    gemm_inplace<<<dim3((N + 31) / 32), dim3(256), 0, stream>>>(out, W, Xr, N);
    gemm_inplace<<<dim3((N + 31) / 32), dim3(256), 0, stream>>>(
        out + (size_t)N * CC, W, Xi, N);
}

// Round 6
// 365.162 us; speedup vs baseline: 3.9997x; 1.2484x over previous
//
#include <hip/hip_runtime.h>
#include <cstddef>

#define CC 128  // channels

// ===========================================================================
// CSR build: histogram -> 3-kernel parallel scan -> fill
// ===========================================================================

__global__ __launch_bounds__(256) void hist_rows(
    const int* __restrict__ row, int* __restrict__ counts, int E)
{
    const int e = blockIdx.x * 256 + threadIdx.x;
    if (e < E) atomicAdd(counts + row[e], 1);
}

// Per-block sum of 256 counts -> bsum[block]
__global__ __launch_bounds__(256) void scan_block_reduce(
    const int* __restrict__ counts, int* __restrict__ bsum, int N)
{
    __shared__ int s[256];
    const int t = threadIdx.x;
    const int idx = blockIdx.x * 256 + t;
    s[t] = (idx < N) ? counts[idx] : 0;
    __syncthreads();
    #pragma unroll
    for (int off = 128; off > 0; off >>= 1) {
        if (t < off) s[t] += s[t + off];
        __syncthreads();
    }
    if (t == 0) bsum[blockIdx.x] = s[0];
}

// Exclusive scan of NB (<=256) block sums, single block.
__global__ __launch_bounds__(256) void scan_bsum(
    const int* __restrict__ bsum, int* __restrict__ bpre, int NB)
{
    __shared__ int s[256];
    const int t = threadIdx.x;
    s[t] = (t < NB) ? bsum[t] : 0;
    __syncthreads();
    #pragma unroll
    for (int off = 1; off < 256; off <<= 1) {
        const int v = s[t];
        const int u = (t >= off) ? s[t - off] : 0;
        __syncthreads();
        s[t] = v + u;
        __syncthreads();
    }
    if (t < NB) bpre[t] = t ? s[t - 1] : 0;
}

// Block-local exclusive scan + block prefix -> offsets
__global__ __launch_bounds__(256) void scan_final(
    const int* __restrict__ counts, const int* __restrict__ bpre,
    int* __restrict__ offsets, int N)
{
    __shared__ int s[256];
    const int t = threadIdx.x;
    const int idx = blockIdx.x * 256 + t;
    const int v = (idx < N) ? counts[idx] : 0;
    s[t] = v;
    __syncthreads();
    #pragma unroll
    for (int off = 1; off < 256; off <<= 1) {
        const int a = s[t];
        const int u = (t >= off) ? s[t - off] : 0;
        __syncthreads();
        s[t] = a + u;
        __syncthreads();
    }
    if (idx < N) offsets[idx] = bpre[blockIdx.x] + s[t] - v;  // exclusive
}

// Scatter packed edge records {col, lr, li, 0} into CSR slots.
__global__ __launch_bounds__(256) void fill_csr(
    const int* __restrict__ row, const int* __restrict__ col,
    const float* __restrict__ Lr, const float* __restrict__ Li,
    const int* __restrict__ offsets, int* __restrict__ cursor,
    int4* __restrict__ meta, int E)
{
    const int e = blockIdx.x * 256 + threadIdx.x;
    if (e >= E) return;
    const int r = row[e];
    const int pos = offsets[r] + atomicAdd(cursor + r, 1);
    meta[pos] = make_int4(col[e], __float_as_int(Lr[e]), __float_as_int(Li[e]), 0);
}

// ===========================================================================
// Y = [Xr;Xi] @ W  (2N rows, no residual). 32-row x 128-col tile per block.
// ===========================================================================
__global__ __launch_bounds__(256) void gemm_xw(
    const float* __restrict__ Xr, const float* __restrict__ Xi,
    const float* __restrict__ W, float* __restrict__ Y, int N)
{
    __shared__ float Ws[64 * CC];       // 32 KB (one 64-row K-chunk of W)
    __shared__ float AsT[CC][36];       // 18 KB, [k][r]
    const int t = threadIdx.x;
    const int m0 = blockIdx.x * 32;
    const int M = 2 * N;

    for (int ch = t; ch < 1024; ch += 256) {
        const int r  = ch >> 5;
        const int k0 = (ch & 31) * 4;
        const int m  = m0 + r;
        float4 q = make_float4(0.f, 0.f, 0.f, 0.f);
        if (m < M) {
            const float* src = (m < N) ? (Xr + (size_t)m * CC)
                                       : (Xi + (size_t)(m - N) * CC);
            q = *(const float4*)(src + k0);
        }
        AsT[k0 + 0][r] = q.x;
        AsT[k0 + 1][r] = q.y;
        AsT[k0 + 2][r] = q.z;
        AsT[k0 + 3][r] = q.w;
    }

    const int cg = t & 31;
    const int rs = t >> 5;
    float s[4][4];
    #pragma unroll
    for (int a = 0; a < 4; ++a)
        #pragma unroll
        for (int b = 0; b < 4; ++b) s[a][b] = 0.f;

    for (int kc = 0; kc < 2; ++kc) {
        __syncthreads();
        {
            const float4* src = (const float4*)(W + (size_t)kc * 64 * CC);
            float4* dst = (float4*)Ws;
            #pragma unroll
            for (int i = 0; i < 8; ++i) dst[t + 256 * i] = src[t + 256 * i];
        }
        __syncthreads();

        #pragma unroll 4
        for (int kk = 0; kk < 64; ++kk) {
            const int k = kc * 64 + kk;
            const float4 av = *(const float4*)&AsT[k][rs * 4];
            const float4 wv = *(const float4*)&Ws[kk * CC + cg * 4];
            const float ar[4] = {av.x, av.y, av.z, av.w};
            const float wc[4] = {wv.x, wv.y, wv.z, wv.w};
            #pragma unroll
            for (int a = 0; a < 4; ++a)
                #pragma unroll
                for (int b = 0; b < 4; ++b) s[a][b] += ar[a] * wc[b];
        }
    }

    #pragma unroll
    for (int a = 0; a < 4; ++a) {
        const int m = m0 + rs * 4 + a;
        if (m >= M) continue;
        float4 o;
        o.x = s[a][0]; o.y = s[a][1]; o.z = s[a][2]; o.w = s[a][3];
        *(float4*)(Y + (size_t)m * CC + cg * 4) = o;
    }
}

// ===========================================================================
// Fused gather: out[n] = sum_e L_e * Y[col_e] + X[n]  (complex), 1 wave/node,
// 2 ch/lane. 4-edge chunks with explicit meta prefetch to break the
// meta->addr->load serial chain.
// ===========================================================================
__device__ __forceinline__ void edge_acc(
    const int4 m, const float* __restrict__ Yr, const float* __restrict__ Yi,
    int lane, float2& aR, float2& aI)
{
    const float2 yr = *(const float2*)(Yr + (size_t)m.x * CC + 2 * lane);
    const float2 yi = *(const float2*)(Yi + (size_t)m.x * CC + 2 * lane);
    const float lr = __int_as_float(m.y);
    const float li = __int_as_float(m.z);
    aR.x += lr * yr.x - li * yi.x;
    aR.y += lr * yr.y - li * yi.y;
    aI.x += li * yr.x + lr * yi.x;
    aI.y += li * yr.y + lr * yi.y;
}

__global__ __launch_bounds__(256) void gather_fused(
    const float* __restrict__ Y,        // [2N][128]: rows 0..N real, N..2N imag
    const float* __restrict__ Xr, const float* __restrict__ Xi,
    const int* __restrict__ offsets, const int4* __restrict__ meta,
    float* __restrict__ out, int N, int E)
{
    const int n = blockIdx.x * 4 + (threadIdx.x >> 6);
    if (n >= N) return;
    const int lane = threadIdx.x & 63;
    const float* Yr = Y;
    const float* Yi = Y + (size_t)N * CC;
    const int start = offsets[n];
    const int end   = (n + 1 < N) ? offsets[n + 1] : E;
    const int Em1 = E - 1;

    // residual init
    float2 aR = *(const float2*)(Xr + (size_t)n * CC + 2 * lane);
    float2 aI = *(const float2*)(Xi + (size_t)n * CC + 2 * lane);

    int4 m0 = meta[min(start + 0, Em1)];
    int4 m1 = meta[min(start + 1, Em1)];
    int4 m2 = meta[min(start + 2, Em1)];
    int4 m3 = meta[min(start + 3, Em1)];

    int j = start;
    for (; j + 4 <= end; j += 4) {
        // prefetch next chunk's meta before consuming this chunk
        const int4 n0 = meta[min(j + 4, Em1)];
        const int4 n1 = meta[min(j + 5, Em1)];
        const int4 n2 = meta[min(j + 6, Em1)];
        const int4 n3 = meta[min(j + 7, Em1)];
        // 8 independent Y-row gathers (addresses already in regs)
        const float2 yr0 = *(const float2*)(Yr + (size_t)m0.x * CC + 2 * lane);
        const float2 yi0 = *(const float2*)(Yi + (size_t)m0.x * CC + 2 * lane);
        const float2 yr1 = *(const float2*)(Yr + (size_t)m1.x * CC + 2 * lane);
        const float2 yi1 = *(const float2*)(Yi + (size_t)m1.x * CC + 2 * lane);
        const float2 yr2 = *(const float2*)(Yr + (size_t)m2.x * CC + 2 * lane);
        const float2 yi2 = *(const float2*)(Yi + (size_t)m2.x * CC + 2 * lane);
        const float2 yr3 = *(const float2*)(Yr + (size_t)m3.x * CC + 2 * lane);
        const float2 yi3 = *(const float2*)(Yi + (size_t)m3.x * CC + 2 * lane);
        {
            const float lr = __int_as_float(m0.y), li = __int_as_float(m0.z);
            aR.x += lr * yr0.x - li * yi0.x; aR.y += lr * yr0.y - li * yi0.y;
            aI.x += li * yr0.x + lr * yi0.x; aI.y += li * yr0.y + lr * yi0.y;
        }
        {
            const float lr = __int_as_float(m1.y), li = __int_as_float(m1.z);
            aR.x += lr * yr1.x - li * yi1.x; aR.y += lr * yr1.y - li * yi1.y;
            aI.x += li * yr1.x + lr * yi1.x; aI.y += li * yr1.y + lr * yi1.y;
        }
        {
            const float lr = __int_as_float(m2.y), li = __int_as_float(m2.z);
            aR.x += lr * yr2.x - li * yi2.x; aR.y += lr * yr2.y - li * yi2.y;
            aI.x += li * yr2.x + lr * yi2.x; aI.y += li * yr2.y + lr * yi2.y;
        }
        {
            const float lr = __int_as_float(m3.y), li = __int_as_float(m3.z);
            aR.x += lr * yr3.x - li * yi3.x; aR.y += lr * yr3.y - li * yi3.y;
            aI.x += li * yr3.x + lr * yi3.x; aI.y += li * yr3.y + lr * yi3.y;
        }
        m0 = n0; m1 = n1; m2 = n2; m3 = n3;
    }
    const int r = end - j;
    if (r > 0) edge_acc(m0, Yr, Yi, lane, aR, aI);
    if (r > 1) edge_acc(m1, Yr, Yi, lane, aR, aI);
    if (r > 2) edge_acc(m2, Yr, Yi, lane, aR, aI);

    *(float2*)(out + (size_t)n * CC + 2 * lane) = aR;
    *(float2*)(out + ((size_t)n + N) * CC + 2 * lane) = aI;
}

// ===========================================================================
// Round-4 fallback kernels (unchanged, proven)
// ===========================================================================
__global__ __launch_bounds__(256) void gather_nodes(
    const float* __restrict__ Xr, const float* __restrict__ Xi,
    const int* __restrict__ offsets, const int4* __restrict__ meta,
    float* __restrict__ out, int N, int E)
{
    const int n = blockIdx.x * 4 + (threadIdx.x >> 6);
    if (n >= N) return;
    const int lane = threadIdx.x & 63;
    const int start = offsets[n];
    const int end   = (n + 1 < N) ? offsets[n + 1] : E;
    float2 aR = make_float2(0.f, 0.f);
    float2 aI = make_float2(0.f, 0.f);
    for (int j = start; j < end; ++j) {
        const int4 m0 = meta[j];
        const float2 xr0 = *(const float2*)(Xr + (size_t)m0.x * CC + 2 * lane);
        const float2 xi0 = *(const float2*)(Xi + (size_t)m0.x * CC + 2 * lane);
        const float lr0 = __int_as_float(m0.y), li0 = __int_as_float(m0.z);
        aR.x += lr0 * xr0.x - li0 * xi0.x;
        aR.y += lr0 * xr0.y - li0 * xi0.y;
        aI.x += li0 * xr0.x + lr0 * xi0.x;
        aI.y += li0 * xr0.y + lr0 * xi0.y;
    }
    *(float2*)(out + (size_t)n * CC + 2 * lane) = aR;
    *(float2*)(out + ((size_t)n + N) * CC + 2 * lane) = aI;
}

__global__ __launch_bounds__(256) void scatter_edges(
    const float* __restrict__ Xr, const float* __restrict__ Xi,
    const float* __restrict__ Lr, const float* __restrict__ Li,
    const int* __restrict__ row, const int* __restrict__ col,
    float* __restrict__ out, int N, int E)
{
    const int e = blockIdx.x * 4 + (threadIdx.x >> 6);
    if (e >= E) return;
    const int lane = threadIdx.x & 63;
    const int r = row[e], c = col[e];
    const float lr = Lr[e];
    const float li = Li[e];
    const float2 xr = *(const float2*)(Xr + (size_t)c * CC + 2 * lane);
    const float2 xi = *(const float2*)(Xi + (size_t)c * CC + 2 * lane);
    float* pr = out + (size_t)r * CC + 2 * lane;
    float* pi = out + ((size_t)r + N) * CC + 2 * lane;
    unsafeAtomicAdd(pr,     lr * xr.x - li * xi.x);
    unsafeAtomicAdd(pr + 1, lr * xr.y - li * xi.y);
    unsafeAtomicAdd(pi,     li * xr.x + lr * xi.x);
    unsafeAtomicAdd(pi + 1, li * xr.y + lr * xi.y);
}

__global__ __launch_bounds__(256) void gemm_inplace(
    float* __restrict__ io, const float* __restrict__ W,
    const float* __restrict__ Xp, int N)
{
    __shared__ float Ws[64 * CC];
    __shared__ float AsT[CC][36];
    const int t = threadIdx.x;
    const int m0 = blockIdx.x * 32;

    for (int ch = t; ch < 1024; ch += 256) {
        const int r  = ch >> 5;
        const int k0 = (ch & 31) * 4;
        const int m  = m0 + r;
        float4 q = make_float4(0.f, 0.f, 0.f, 0.f);
        if (m < N) q = *(const float4*)(io + (size_t)m * CC + k0);
        AsT[k0 + 0][r] = q.x;
        AsT[k0 + 1][r] = q.y;
        AsT[k0 + 2][r] = q.z;
        AsT[k0 + 3][r] = q.w;
    }

    const int cg = t & 31;
    const int rs = t >> 5;
    float s[4][4];
    #pragma unroll
    for (int a = 0; a < 4; ++a)
        #pragma unroll
        for (int b = 0; b < 4; ++b) s[a][b] = 0.f;

    for (int kc = 0; kc < 2; ++kc) {
        __syncthreads();
        {
            const float4* src = (const float4*)(W + (size_t)kc * 64 * CC);
            float4* dst = (float4*)Ws;
            #pragma unroll
            for (int i = 0; i < 8; ++i) dst[t + 256 * i] = src[t + 256 * i];
        }
        __syncthreads();
        #pragma unroll 4
        for (int kk = 0; kk < 64; ++kk) {
            const int k = kc * 64 + kk;
            const float4 av = *(const float4*)&AsT[k][rs * 4];
            const float4 wv = *(const float4*)&Ws[kk * CC + cg * 4];
            const float ar[4] = {av.x, av.y, av.z, av.w};
            const float wc[4] = {wv.x, wv.y, wv.z, wv.w};
            #pragma unroll
            for (int a = 0; a < 4; ++a)
                #pragma unroll
                for (int b = 0; b < 4; ++b) s[a][b] += ar[a] * wc[b];
        }
    }

    #pragma unroll
    for (int a = 0; a < 4; ++a) {
        const int m = m0 + rs * 4 + a;
        if (m >= N) continue;
        const float4 xv = *(const float4*)(Xp + (size_t)m * CC + cg * 4);
        float4 o;
        o.x = s[a][0] + xv.x;
        o.y = s[a][1] + xv.y;
        o.z = s[a][2] + xv.z;
        o.w = s[a][3] + xv.w;
        *(float4*)(io + (size_t)m * CC + cg * 4) = o;
    }
}

// ===========================================================================
extern "C" void kernel_launch(void* const* d_in, const int* in_sizes, int n_in,
                              void* d_out, int out_size, void* d_ws, size_t ws_size,
                              hipStream_t stream)
{
    const float* Xr = (const float*)d_in[0];
    const float* Xi = (const float*)d_in[1];
    const float* Lr = (const float*)d_in[2];
    const float* Li = (const float*)d_in[3];
    const float* W  = (const float*)d_in[4];
    const int* row = (const int*)d_in[5];
    const int* col = (const int*)d_in[6];
    float* out = (float*)d_out;

    const int N = in_sizes[0] / CC;     // 50000
    const int E = in_sizes[2];          // 800000
    const int NB = (N + 255) / 256;     // scan blocks (196 <= 256)

    const size_t y_bytes    = (size_t)2 * N * CC * sizeof(float);
    const size_t meta_bytes = (size_t)E * 16;
    const size_t int_bytes  = ((size_t)3 * N + 512) * sizeof(int);
    const size_t need_csr   = meta_bytes + int_bytes;
    const size_t need_fused = y_bytes + need_csr;

    if (ws_size >= need_fused) {
        float* Y      = (float*)d_ws;
        int4*  meta   = (int4*)((char*)d_ws + y_bytes);
        int*   counts = (int*)((char*)d_ws + y_bytes + meta_bytes);
        int*   cursor  = counts + N;
        int*   offsets = cursor + N;
        int*   bsum    = offsets + N;
        int*   bpre    = bsum + 256;

        hipMemsetAsync(counts, 0, (size_t)2 * N * sizeof(int), stream);
        hist_rows<<<dim3((E + 255) / 256), dim3(256), 0, stream>>>(row, counts, E);
        scan_block_reduce<<<dim3(NB), dim3(256), 0, stream>>>(counts, bsum, N);
        scan_bsum<<<dim3(1), dim3(256), 0, stream>>>(bsum, bpre, NB);
        scan_final<<<dim3(NB), dim3(256), 0, stream>>>(counts, bpre, offsets, N);
        fill_csr<<<dim3((E + 255) / 256), dim3(256), 0, stream>>>(
            row, col, Lr, Li, offsets, cursor, meta, E);
        gemm_xw<<<dim3((2 * N + 31) / 32), dim3(256), 0, stream>>>(Xr, Xi, W, Y, N);
        gather_fused<<<dim3((N + 3) / 4), dim3(256), 0, stream>>>(
            Y, Xr, Xi, offsets, meta, out, N, E);
    } else if (ws_size >= need_csr) {
        int4* meta    = (int4*)d_ws;
        int*  counts  = (int*)((char*)d_ws + meta_bytes);
        int*  cursor  = counts + N;
        int*  offsets = cursor + N;
        int*  bsum    = offsets + N;
        int*  bpre    = bsum + 256;

        hipMemsetAsync(counts, 0, (size_t)2 * N * sizeof(int), stream);
        hist_rows<<<dim3((E + 255) / 256), dim3(256), 0, stream>>>(row, counts, E);
        scan_block_reduce<<<dim3(NB), dim3(256), 0, stream>>>(counts, bsum, N);
        scan_bsum<<<dim3(1), dim3(256), 0, stream>>>(bsum, bpre, NB);
        scan_final<<<dim3(NB), dim3(256), 0, stream>>>(counts, bpre, offsets, N);
        fill_csr<<<dim3((E + 255) / 256), dim3(256), 0, stream>>>(
            row, col, Lr, Li, offsets, cursor, meta, E);
        gather_nodes<<<dim3((N + 3) / 4), dim3(256), 0, stream>>>(
            Xr, Xi, offsets, meta, out, N, E);
        gemm_inplace<<<dim3((N + 31) / 32), dim3(256), 0, stream>>>(out, W, Xr, N);
        gemm_inplace<<<dim3((N + 31) / 32), dim3(256), 0, stream>>>(
            out + (size_t)N * CC, W, Xi, N);
    } else {
        hipMemsetAsync(out, 0, (size_t)2 * N * CC * sizeof(float), stream);
        scatter_edges<<<dim3((E + 3) / 4), dim3(256), 0, stream>>>(
            Xr, Xi, Lr, Li, row, col, out, N, E);
        gemm_inplace<<<dim3((N + 31) / 32), dim3(256), 0, stream>>>(out, W, Xr, N);
        gemm_inplace<<<dim3((N + 31) / 32), dim3(256), 0, stream>>>(
            out + (size_t)N * CC, W, Xi, N);
    }
}